// Round 1
// baseline (292.957 us; speedup 1.0000x reference)
//
#include <hip/hip_runtime.h>

// ClassicPINN forward: 1M points x (3 -> 8x7 -> 16x3 -> 32x3 -> 16 -> 3), tanh
// between layers. VALU-compute-bound (no fp32 MFMA on CDNA4).
// Strategy: 1 thread = 1 point; fully unrolled layers; activations in
// registers (compile-time indices only); weights via wave-uniform const
// indices -> compiler emits scalar s_load (SMEM pipe) feeding v_fmac_f32
// with the SGPR operand, keeping the VALU pipe purely on math.

#define NPTS 1048576

struct PinnParams {
    const float* W[15];
    const float* B[15];
};

__device__ __forceinline__ float fast_tanh(float x) {
    // tanh(x) = 1 - 2/(exp(2x)+1); exp(2x) = exp2(x * 2*log2(e)).
    // Clamp at +-9.5: tanh(9.5) rounds to 1.0f, and our formula gives the
    // same rounding (2*rcp(exp(19)+1) ~= 1.1e-8 -> 1.0f). No overflow/NaN.
    x = fminf(fmaxf(x, -9.5f), 9.5f);
    float e = __builtin_amdgcn_exp2f(x * 2.8853900817779268f);
    return 1.0f - 2.0f * __builtin_amdgcn_rcpf(e + 1.0f);
}

template <int IN, int OUT, int LAYER, bool TANH>
__device__ __forceinline__ void layer(const PinnParams& p, const float* h, float* o) {
    const float* __restrict__ W = p.W[LAYER];  // wave-uniform, read-only
    const float* __restrict__ B = p.B[LAYER];
#pragma unroll
    for (int j = 0; j < OUT; ++j) {
        float acc = B[j];
#pragma unroll
        for (int k = 0; k < IN; ++k)
            acc = fmaf(W[j * IN + k], h[k], acc);  // W uniform -> s_load + v_fmac
        o[j] = TANH ? fast_tanh(acc) : acc;
    }
}

__global__ __launch_bounds__(256) void pinn_fwd(const float* __restrict__ coords,
                                                PinnParams p,
                                                float* __restrict__ out) {
    const int i = blockIdx.x * 256 + threadIdx.x;  // grid covers NPTS exactly
    float h0[3];
    h0[0] = coords[3 * i + 0];
    h0[1] = coords[3 * i + 1];
    h0[2] = coords[3 * i + 2];

    float a[32], c[32];  // ping-pong activation buffers, static indices only
    layer<3, 8, 0, true>(p, h0, a);
    layer<8, 8, 1, true>(p, a, c);
    layer<8, 8, 2, true>(p, c, a);
    layer<8, 8, 3, true>(p, a, c);
    layer<8, 8, 4, true>(p, c, a);
    layer<8, 8, 5, true>(p, a, c);
    layer<8, 8, 6, true>(p, c, a);
    layer<8, 16, 7, true>(p, a, c);
    layer<16, 16, 8, true>(p, c, a);
    layer<16, 16, 9, true>(p, a, c);
    layer<16, 32, 10, true>(p, c, a);
    layer<32, 32, 11, true>(p, a, c);
    layer<32, 32, 12, true>(p, c, a);
    layer<32, 16, 13, true>(p, a, c);
    layer<16, 3, 14, false>(p, c, a);

    // reference returns (h[:,0:1], h[:,1:2], h[:,2:3]) -> concatenated flat
    out[i] = a[0];
    out[NPTS + i] = a[1];
    out[2 * NPTS + i] = a[2];
}

extern "C" void kernel_launch(void* const* d_in, const int* in_sizes, int n_in,
                              void* d_out, int out_size, void* d_ws, size_t ws_size,
                              hipStream_t stream) {
    const float* coords = (const float*)d_in[0];
    PinnParams p;
    for (int l = 0; l < 15; ++l) {
        p.W[l] = (const float*)d_in[1 + 2 * l];
        p.B[l] = (const float*)d_in[2 + 2 * l];
    }
    pinn_fwd<<<NPTS / 256, 256, 0, stream>>>(coords, p, (float*)d_out);
}

// Round 4
// 291.527 us; speedup vs baseline: 1.0049x; 1.0049x over previous
//
#include <hip/hip_runtime.h>

// ClassicPINN forward, round 2 kernel (3rd submit — two benches lost to GPU
// acquisition timeouts; kernel has never run).
// P=2 points/thread, j-loop restructure. Each output-neuron j: load W row as
// float4 (uniform addr -> L1 broadcast), reuse across P points -> 8x fewer
// weight fetches/point, 2 independent FMA chains (hides dependent-FMA latency
// that the 36-VGPR round-1 build exposed).

#define NPTS 1048576
#define P 2  // points per thread

struct PinnParams {
    const float* W[15];
    const float* B[15];
};

__device__ __forceinline__ float fast_tanh(float x) {
    // tanh(x) = 1 - 2/(exp(2x)+1); exp(2x)=exp2(x*2*log2e). Clamp +-9.5
    // saturates to 1.0f exactly like tanhf. Same formula as round 1 (absmax
    // 9.8e-4, passed).
    x = fminf(fmaxf(x, -9.5f), 9.5f);
    float e = __builtin_amdgcn_exp2f(x * 2.8853900817779268f);
    return 1.0f - 2.0f * __builtin_amdgcn_rcpf(e + 1.0f);
}

// h, o are [P][32] register arrays; only [*][0..IN/OUT) entries are live.
template <int IN, int OUT, bool TANH>
__device__ __forceinline__ void layerP(const float* __restrict__ W,
                                       const float* __restrict__ B,
                                       const float (*h)[32], float (*o)[32]) {
    static_assert(IN % 4 == 0, "IN must be multiple of 4");
#pragma unroll
    for (int j = 0; j < OUT; ++j) {
        const float b = B[j];
        float acc[P];
#pragma unroll
        for (int p = 0; p < P; ++p) acc[p] = b;
#pragma unroll
        for (int k = 0; k < IN; k += 4) {
            // uniform address, 16B-aligned (IN multiple of 4) -> one
            // global_load_dwordx4 per wave, L1-broadcast (weights = 17.5KB).
            const float4 w = *reinterpret_cast<const float4*>(W + j * IN + k);
#pragma unroll
            for (int p = 0; p < P; ++p) {
                acc[p] = fmaf(w.x, h[p][k + 0], acc[p]);
                acc[p] = fmaf(w.y, h[p][k + 1], acc[p]);
                acc[p] = fmaf(w.z, h[p][k + 2], acc[p]);
                acc[p] = fmaf(w.w, h[p][k + 3], acc[p]);
            }
        }
#pragma unroll
        for (int p = 0; p < P; ++p) o[p][j] = TANH ? fast_tanh(acc[p]) : acc[p];
    }
}

// First layer: IN=3 (not float4-able), scalar weight loads (24 weights only).
__device__ __forceinline__ void layer0(const float* __restrict__ W,
                                       const float* __restrict__ B,
                                       const float (*h)[32], float (*o)[32]) {
#pragma unroll
    for (int j = 0; j < 8; ++j) {
        const float w0 = W[3 * j + 0], w1 = W[3 * j + 1], w2 = W[3 * j + 2];
        const float b = B[j];
#pragma unroll
        for (int p = 0; p < P; ++p) {
            float acc = fmaf(w0, h[p][0], b);
            acc = fmaf(w1, h[p][1], acc);
            acc = fmaf(w2, h[p][2], acc);
            o[p][j] = fast_tanh(acc);
        }
    }
}

__global__ __launch_bounds__(256, 2) void pinn_fwd(const float* __restrict__ coords,
                                                   PinnParams prm,
                                                   float* __restrict__ out) {
    const int t = blockIdx.x * 256 + threadIdx.x;
    const int i0 = t * P;

    float a[P][32], c[P][32];  // ping-pong register activations, static idx only
#pragma unroll
    for (int p = 0; p < P; ++p) {
        a[p][0] = coords[3 * (i0 + p) + 0];
        a[p][1] = coords[3 * (i0 + p) + 1];
        a[p][2] = coords[3 * (i0 + p) + 2];
    }

    layer0(prm.W[0], prm.B[0], a, c);                      // 3 -> 8
    layerP<8, 8, true>(prm.W[1], prm.B[1], c, a);
    layerP<8, 8, true>(prm.W[2], prm.B[2], a, c);
    layerP<8, 8, true>(prm.W[3], prm.B[3], c, a);
    layerP<8, 8, true>(prm.W[4], prm.B[4], a, c);
    layerP<8, 8, true>(prm.W[5], prm.B[5], c, a);
    layerP<8, 8, true>(prm.W[6], prm.B[6], a, c);
    layerP<8, 16, true>(prm.W[7], prm.B[7], c, a);         // 8 -> 16
    layerP<16, 16, true>(prm.W[8], prm.B[8], a, c);
    layerP<16, 16, true>(prm.W[9], prm.B[9], c, a);
    layerP<16, 32, true>(prm.W[10], prm.B[10], a, c);      // 16 -> 32
    layerP<32, 32, true>(prm.W[11], prm.B[11], c, a);
    layerP<32, 32, true>(prm.W[12], prm.B[12], a, c);
    layerP<32, 16, true>(prm.W[13], prm.B[13], c, a);      // 32 -> 16
    layerP<16, 3, false>(prm.W[14], prm.B[14], a, c);      // 16 -> 3, no tanh

    // outputs: (h[:,0], h[:,1], h[:,2]) concatenated; adjacent points -> float2
    *reinterpret_cast<float2*>(out + i0) = make_float2(c[0][0], c[1][0]);
    *reinterpret_cast<float2*>(out + NPTS + i0) = make_float2(c[0][1], c[1][1]);
    *reinterpret_cast<float2*>(out + 2 * NPTS + i0) = make_float2(c[0][2], c[1][2]);
}

extern "C" void kernel_launch(void* const* d_in, const int* in_sizes, int n_in,
                              void* d_out, int out_size, void* d_ws, size_t ws_size,
                              hipStream_t stream) {
    const float* coords = (const float*)d_in[0];
    PinnParams prm;
    for (int l = 0; l < 15; ++l) {
        prm.W[l] = (const float*)d_in[1 + 2 * l];
        prm.B[l] = (const float*)d_in[2 + 2 * l];
    }
    pinn_fwd<<<NPTS / (256 * P), 256, 0, stream>>>(coords, prm, (float*)d_out);
}

// Round 6
// 275.481 us; speedup vs baseline: 1.0634x; 1.0582x over previous
//
#include <hip/hip_runtime.h>

// ClassicPINN forward, round 5 kernel (2nd submit — round-5 bench lost to GPU
// acquisition timeout; this exact source has never run).
// Diagnosis from round 4 (191us, VGPR=68-granules~136, VALUBusy 86%):
// no spills; ~2x gap to the ~93us scalar-VALU floor = weight-load latency
// exposure (1036 uniform VMEM loads/thread, 3 waves/SIMD) + scalar-rate FMA.
// Fixes: (1) pack the 2 points/thread into f32x2 -> v_pk_fma_f32 (the only
// path to the 157TF fp32 rate; scalar v_fma is 78.6TF), (2) weights+biases
// staged to LDS once/block, read as uniform-addr ds_read_b128 (broadcast,
// conflict-free, lower latency than L1 vector loads).

#define NPTS 1048576
#define P 2  // points per thread, packed into f32x2 lanes {pt0, pt1}

typedef float f32x2 __attribute__((ext_vector_type(2)));

struct PinnParams {
    const float* W[15];
    const float* B[15];
};

// Layer geometry (floats), compile-time.
__constant__ constexpr int kIN[15]   = {3, 8, 8, 8, 8, 8, 8, 8, 16, 16, 16, 32, 32, 32, 16};
__constant__ constexpr int kOUT[15]  = {8, 8, 8, 8, 8, 8, 8, 16, 16, 16, 32, 32, 32, 16, 3};
__constant__ constexpr int kWSZ[15]  = {24, 64, 64, 64, 64, 64, 64, 128, 256, 256, 512, 1024, 1024, 512, 48};
__constant__ constexpr int kWOFF[15] = {0, 24, 88, 152, 216, 280, 344, 408, 536, 792, 1048, 1560, 2584, 3608, 4120};
__constant__ constexpr int kBOFF[15] = {0, 8, 16, 24, 32, 40, 48, 56, 72, 88, 104, 136, 168, 200, 216};
#define WTOT 4168
#define BTOT 219

__device__ __forceinline__ float fast_tanh(float x) {
    // tanh(x) = 1 - 2/(exp(2x)+1); exp(2x)=exp2(x*2*log2e). Clamp +-9.5
    // (v_med3_f32) saturates to 1.0f exactly like tanhf. Bit-identical to
    // rounds 1/4 (absmax 9.77e-4, passed).
    x = __builtin_amdgcn_fmed3f(x, -9.5f, 9.5f);
    float e = __builtin_amdgcn_exp2f(x * 2.8853900817779268f);
    return 1.0f - 2.0f * __builtin_amdgcn_rcpf(e + 1.0f);
}

__device__ __forceinline__ f32x2 tanh2(f32x2 x) {
    return f32x2{fast_tanh(x.x), fast_tanh(x.y)};
}

// One layer, IN multiple of 4. h/o: f32x2[32] register arrays (static idx).
template <int L, bool TANH>
__device__ __forceinline__ void layerL(const float* __restrict__ ldsw,
                                       const float* __restrict__ ldsb,
                                       const f32x2* h, f32x2* o) {
    constexpr int IN = kIN[L], OUT = kOUT[L], WO = kWOFF[L], BO = kBOFF[L];
    static_assert(IN % 4 == 0, "use layer0 for IN=3");
#pragma unroll
    for (int j = 0; j < OUT; ++j) {
        const float b = ldsb[BO + j];          // uniform ds_read_b32 broadcast
        f32x2 acc = {b, b};
#pragma unroll
        for (int k = 0; k < IN; k += 4) {
            // uniform-addr ds_read_b128 broadcast (conflict-free)
            const float4 w = *reinterpret_cast<const float4*>(ldsw + WO + j * IN + k);
            acc = __builtin_elementwise_fma(f32x2{w.x, w.x}, h[k + 0], acc);
            acc = __builtin_elementwise_fma(f32x2{w.y, w.y}, h[k + 1], acc);
            acc = __builtin_elementwise_fma(f32x2{w.z, w.z}, h[k + 2], acc);
            acc = __builtin_elementwise_fma(f32x2{w.w, w.w}, h[k + 3], acc);
        }
        o[j] = TANH ? tanh2(acc) : acc;
    }
}

// First layer: IN=3, scalar ds_reads (24 weights).
__device__ __forceinline__ void layer0(const float* __restrict__ ldsw,
                                       const float* __restrict__ ldsb,
                                       const f32x2* h, f32x2* o) {
#pragma unroll
    for (int j = 0; j < 8; ++j) {
        const float w0 = ldsw[3 * j], w1 = ldsw[3 * j + 1], w2 = ldsw[3 * j + 2];
        const float b = ldsb[j];
        f32x2 acc = {b, b};
        acc = __builtin_elementwise_fma(f32x2{w0, w0}, h[0], acc);
        acc = __builtin_elementwise_fma(f32x2{w1, w1}, h[1], acc);
        acc = __builtin_elementwise_fma(f32x2{w2, w2}, h[2], acc);
        o[j] = tanh2(acc);
    }
}

__global__ __launch_bounds__(256, 2) void pinn_fwd(const float* __restrict__ coords,
                                                   PinnParams prm,
                                                   float* __restrict__ out) {
    __shared__ __align__(16) float ldsw[WTOT];
    __shared__ float ldsb[BTOT];

    // ---- stage weights + biases to LDS (once per block) ----
    const int tid = threadIdx.x;
#pragma unroll
    for (int l = 0; l < 15; ++l) {
        const float* __restrict__ W = prm.W[l];
        for (int idx = tid; idx < kWSZ[l]; idx += 256) ldsw[kWOFF[l] + idx] = W[idx];
        const float* __restrict__ B = prm.B[l];
        if (tid < kOUT[l]) ldsb[kBOFF[l] + tid] = B[tid];
    }
    __syncthreads();

    // ---- load 2 points, pack features as f32x2 {pt0, pt1} ----
    const int t = blockIdx.x * 256 + tid;
    const int i0 = t * P;
    const f32x2* cp = reinterpret_cast<const f32x2*>(coords + 3 * i0);  // 8B aligned
    const f32x2 q0 = cp[0], q1 = cp[1], q2 = cp[2];  // {x0,y0} {z0,x1} {y1,z1}

    f32x2 a[32], c[32];  // ping-pong activations, static indices only
    a[0] = f32x2{q0.x, q1.y};  // {x0, x1}
    a[1] = f32x2{q0.y, q2.x};  // {y0, y1}
    a[2] = f32x2{q1.x, q2.y};  // {z0, z1}

    layer0(ldsw, ldsb, a, c);            // 3 -> 8
    layerL<1, true>(ldsw, ldsb, c, a);
    layerL<2, true>(ldsw, ldsb, a, c);
    layerL<3, true>(ldsw, ldsb, c, a);
    layerL<4, true>(ldsw, ldsb, a, c);
    layerL<5, true>(ldsw, ldsb, c, a);
    layerL<6, true>(ldsw, ldsb, a, c);
    layerL<7, true>(ldsw, ldsb, c, a);   // 8 -> 16
    layerL<8, true>(ldsw, ldsb, a, c);
    layerL<9, true>(ldsw, ldsb, c, a);
    layerL<10, true>(ldsw, ldsb, a, c);  // 16 -> 32
    layerL<11, true>(ldsw, ldsb, c, a);
    layerL<12, true>(ldsw, ldsb, a, c);
    layerL<13, true>(ldsw, ldsb, c, a);  // 32 -> 16
    layerL<14, false>(ldsw, ldsb, a, c); // 16 -> 3, no tanh

    // outputs concatenated: c[j] = {pt0_outj, pt1_outj} -> contiguous pair
    *reinterpret_cast<f32x2*>(out + i0) = c[0];
    *reinterpret_cast<f32x2*>(out + NPTS + i0) = c[1];
    *reinterpret_cast<f32x2*>(out + 2 * NPTS + i0) = c[2];
}

extern "C" void kernel_launch(void* const* d_in, const int* in_sizes, int n_in,
                              void* d_out, int out_size, void* d_ws, size_t ws_size,
                              hipStream_t stream) {
    const float* coords = (const float*)d_in[0];
    PinnParams prm;
    for (int l = 0; l < 15; ++l) {
        prm.W[l] = (const float*)d_in[1 + 2 * l];
        prm.B[l] = (const float*)d_in[2 + 2 * l];
    }
    pinn_fwd<<<NPTS / (256 * P), 256, 0, stream>>>(coords, prm, (float*)d_out);
}